// Round 12
// baseline (110.587 us; speedup 1.0000x reference)
//
#include <hip/hip_runtime.h>
#include <hip/hip_bf16.h>
#include <stdint.h>

#define IN_F  4096
#define OUT_F 11008
#define MTOT  512

#define BM 128
#define BN 64
#define BK 64
#define NKT (IN_F / BK)            // 64 K-tiles
#define B_TILE_B (BN * BK)         // 4096 B (i8)
#define XT_B 8192                  // per [mtile][kt] i8 fragment block: 8 frags x 1 KB
#define SX_OFF ((size_t)MTOT * IN_F)            // 2 MiB: i8 A frags
#define X_WS_BYTES (SX_OFF + MTOT * 4)          // + 2 KiB sx

typedef __attribute__((ext_vector_type(4))) float  f32x4;
typedef __attribute__((ext_vector_type(4))) int    i32x4;
typedef __attribute__((ext_vector_type(2))) unsigned u32x2;
typedef __attribute__((ext_vector_type(4))) unsigned u32x4;
typedef __attribute__((ext_vector_type(8))) __bf16 bf16x8;

// f32 -> bf16 pair, round-to-nearest (fallback path)
__device__ __forceinline__ unsigned pack2bf16_rnd(float lo, float hi) {
    unsigned ulo = __builtin_bit_cast(unsigned, lo) + 0x8000u;
    unsigned uhi = __builtin_bit_cast(unsigned, hi) + 0x8000u;
    return __builtin_amdgcn_perm(uhi, ulo, 0x07060302u);
}
// f32 -> bf16 pair, truncation (fallback path; exact for ints |q|<=127)
__device__ __forceinline__ unsigned pack2bf16_exact(float lo, float hi) {
    return __builtin_amdgcn_perm(__builtin_bit_cast(unsigned, hi),
                                 __builtin_bit_cast(unsigned, lo), 0x07060302u);
}
// 4 int32 (each in [-128,127]) -> 4 packed i8 bytes (low byte of each)
__device__ __forceinline__ unsigned pack4_i8(i32x4 v) {
    unsigned r1 = __builtin_amdgcn_perm((unsigned)v.y, (unsigned)v.x, 0x00000400u);
    unsigned r2 = __builtin_amdgcn_perm((unsigned)v.w, (unsigned)v.z, 0x00000400u);
    return __builtin_amdgcn_perm(r2, r1, 0x05040100u);
}

// LDS-only barrier: B ds ops are the only cross-wave state; global loads
// (A frags, raw B) stay in flight across it.
#define BAR() do {                                                 \
    asm volatile("s_waitcnt lgkmcnt(0)" ::: "memory");             \
    __builtin_amdgcn_s_barrier();                                  \
    __builtin_amdgcn_sched_barrier(0);                             \
} while (0)

// ---- Prepass: per-row i8 quantization of X into MFMA-fragment order ----
// xws layout: [mtile][kt][f = mrow>>4][lane][16B], 8 KB per (mtile,kt).
// Lane l of frag f holds X_q[mtile*128 + f*16 + (l&15)][kt*64 + (l>>4)*16 .. +16].
// sx[row] = rowmax/127 so X ~= sx * Xq exactly elementwise to +-sx/2.
__global__ __launch_bounds__(256)
void xconv_kernel(const float* __restrict__ X, char* __restrict__ xws,
                  float* __restrict__ sx) {
    const int row = (int)blockIdx.x;     // 512 rows
    const int t   = (int)threadIdx.x;    // 256 thr; 16 cols each
    const float* src = X + (size_t)row * IN_F + t * 16;
    f32x4 v0 = *(const f32x4*)(src);
    f32x4 v1 = *(const f32x4*)(src + 4);
    f32x4 v2 = *(const f32x4*)(src + 8);
    f32x4 v3 = *(const f32x4*)(src + 12);

    float m = 0.f;
    #pragma unroll
    for (int i = 0; i < 4; ++i) {
        m = fmaxf(m, fmaxf(fmaxf(fabsf(v0[i]), fabsf(v1[i])),
                           fmaxf(fabsf(v2[i]), fabsf(v3[i]))));
    }
    #pragma unroll
    for (int off = 32; off >= 1; off >>= 1)
        m = fmaxf(m, __shfl_xor(m, off));
    __shared__ float red[4];
    if ((t & 63) == 0) red[t >> 6] = m;
    __syncthreads();
    m = fmaxf(fmaxf(red[0], red[1]), fmaxf(red[2], red[3]));
    m = fmaxf(m, 1e-20f);
    const float inv = 127.0f / m;
    if (t == 0) sx[row] = m * (1.0f / 127.0f);

    i32x4 q0, q1, q2, q3;
    #pragma unroll
    for (int i = 0; i < 4; ++i) {
        q0[i] = (int)__builtin_rintf(v0[i] * inv);
        q1[i] = (int)__builtin_rintf(v1[i] * inv);
        q2[i] = (int)__builtin_rintf(v2[i] * inv);
        q3[i] = (int)__builtin_rintf(v3[i] * inv);
    }
    u32x4 o;
    o.x = pack4_i8(q0); o.y = pack4_i8(q1);
    o.z = pack4_i8(q2); o.w = pack4_i8(q3);

    const int mtile = row >> 7, mrow = row & 127;
    const int f = mrow >> 4, l15 = mrow & 15;
    const int kt = t >> 2;            // col0 = 16t -> kt = col0/64
    const int h  = t & 3;             // (col0>>4)&3
    const int lane = h * 16 + l15;
    *(u32x4*)(xws + ((size_t)(mtile * NKT + kt)) * XT_B + f * 1024
                  + lane * 16) = o;
}

// ---- Main GEMM: BM=128 x BN=64, 2 waves, 64x64 wave tile, i8 MFMA K=64.
//      A: i8 frag-direct from xws (halved bytes). B: raw int32 -> perm-pack
//      i8 -> LDS in FRAGMENT order (16B/lane linear ds ops, conflict-free).
//      CONVERT placed AFTER MFMA so rb's vmcnt-wait drains under the MFMA
//      pipe. R8 XCD mapping and lgkm-only barrier. Int32-exact accumulate;
//      epilogue applies sx[row]/scale[col]. ----
__global__ __launch_bounds__(128, 2)
void qgemm_kernel(const char* __restrict__ xws, const float* __restrict__ sx,
                  const int*   __restrict__ W,
                  const float* __restrict__ scale,
                  const float* __restrict__ bias,
                  float* __restrict__ Out)
{
    __shared__ __align__(16) char smem[2 * B_TILE_B];  // 8 KiB
    char* bufB0 = smem;
    char* bufB1 = smem + B_TILE_B;

    const int tid  = (int)threadIdx.x;
    const int lane = tid & 63;
    const int w    = tid >> 6;

    // XCD mapping (R2/R5/R8-proven): 688 = 8*86 exact; 4 mtiles of one ntile
    // consecutive within an XCD -> W panel L2-shared 4-way.
    const int bid  = (int)blockIdx.x;
    const int lbid = (bid & 7) * 86 + (bid >> 3);
    const int mtile = lbid & 3;
    const int ntile = lbid >> 2;
    const int brow = mtile * BM;
    const int bcol = ntile * BN;

    // B staging slots: 4 frags x 64 lanes = 256 slots x 16B. Thread t owns
    // slots t (frag t>>6) and t+128 (frag (t>>6)+2); slot (f,l) holds
    // W[bcol + f*16 + (l&15)][kt*64 + (l>>4)*16 .. +16] as 16 i8.
    const int f1 = tid >> 6;           // 0..1
    const int l1 = tid & 63;
    const int r1 = bcol + f1 * 16 + (l1 & 15);
    const int kw = (l1 >> 4) * 16;
    const int* Wp1 = W + (size_t)r1 * IN_F + kw;
    const int* Wp2 = Wp1 + (size_t)32 * IN_F;   // slot2 row = r1 + 32

    // Wave w owns A frags f = w*4 + mi.
    const char* xA = xws + (size_t)mtile * (NKT * XT_B) + (w * 4) * 1024
                   + lane * 16;

    i32x4 rb[8];
    i32x4 afE[4], afO[4];
    i32x4 acc[4][4];
    #pragma unroll
    for (int i = 0; i < 4; ++i)
        #pragma unroll
        for (int jj = 0; jj < 4; ++jj)
            acc[i][jj] = (i32x4){0, 0, 0, 0};

    #define LOAD_A(AF, KT)                                                   \
        _Pragma("unroll")                                                    \
        for (int mi = 0; mi < 4; ++mi)                                       \
            AF[mi] = *(const i32x4*)(xA + (size_t)(KT) * XT_B + mi * 1024);

    #define LOAD_B(KT)                                                       \
        _Pragma("unroll")                                                    \
        for (int k = 0; k < 4; ++k) {                                        \
            rb[k]     = *(const i32x4*)(Wp1 + (size_t)(KT) * BK + k * 4);    \
            rb[k + 4] = *(const i32x4*)(Wp2 + (size_t)(KT) * BK + k * 4);    \
        }

    #define CONVERT_B(DSTB)                                                  \
        do {                                                                 \
            u32x4 o1, o2;                                                    \
            o1.x = pack4_i8(rb[0]); o1.y = pack4_i8(rb[1]);                  \
            o1.z = pack4_i8(rb[2]); o1.w = pack4_i8(rb[3]);                  \
            o2.x = pack4_i8(rb[4]); o2.y = pack4_i8(rb[5]);                  \
            o2.z = pack4_i8(rb[6]); o2.w = pack4_i8(rb[7]);                  \
            *(u32x4*)((DSTB) + tid * 16) = o1;                               \
            *(u32x4*)((DSTB) + tid * 16 + 2048) = o2;                        \
        } while (0)

    #define MFMA_PHASE(AF, BUFB)                                             \
        do {                                                                 \
            i32x4 bfr[4];                                                    \
            _Pragma("unroll")                                                \
            for (int ni = 0; ni < 4; ++ni)                                   \
                bfr[ni] = *(const i32x4*)((BUFB) + ni * 1024 + lane * 16);   \
            _Pragma("unroll")                                                \
            for (int mi = 0; mi < 4; ++mi)                                   \
                _Pragma("unroll")                                            \
                for (int ni = 0; ni < 4; ++ni)                               \
                    acc[mi][ni] = __builtin_amdgcn_mfma_i32_16x16x64_i8(     \
                        AF[mi], bfr[ni], acc[mi][ni], 0, 0, 0);              \
        } while (0)

    // ---------- prologue ----------
    LOAD_B(0);
    CONVERT_B(bufB0);          // waits rb(0)
    LOAD_B(1);
    LOAD_A(afE, 0);
    BAR();                     // publish bufB0

    // ---------- main loop: pairs; MFMA before CONVERT (stall under MFMA) ----
    for (int kt2 = 0; kt2 < NKT; kt2 += 2) {
        const bool more = (kt2 + 2 < NKT);

        // ===== even kt = kt2: compute bufB0/afE; fill bufB1 with B(kt2+1) ===
        LOAD_A(afO, kt2 + 1);
        MFMA_PHASE(afE, bufB0);
        CONVERT_B(bufB1);                      // B(kt2+1) from rb
        if (more) LOAD_B(kt2 + 2);
        BAR();                                 // publish bufB1

        // ===== odd kt = kt2+1: compute bufB1/afO; fill bufB0 with B(kt2+2) ==
        if (more) LOAD_A(afE, kt2 + 2);
        MFMA_PHASE(afO, bufB1);
        if (more) {
            CONVERT_B(bufB0);                  // B(kt2+2) from rb
            if (kt2 + 3 < NKT) LOAD_B(kt2 + 3);
            BAR();                             // publish bufB0
        }
    }

    // --- epilogue: out = acc * sx[row]/scale[col] + bias[col] ---
    // C/D mapping: col = lane&15, row = (lane>>4)*4 + j
    #pragma unroll
    for (int ni = 0; ni < 4; ++ni) {
        const int col = bcol + ni * 16 + (lane & 15);
        const float inv = 1.0f / scale[col];
        const float bs  = bias[col];
        #pragma unroll
        for (int mi = 0; mi < 4; ++mi) {
            const int row0 = brow + w * 64 + mi * 16 + ((lane >> 4) << 2);
            const f32x4 sxq = *(const f32x4*)(sx + row0);
            #pragma unroll
            for (int jj = 0; jj < 4; ++jj)
                Out[(size_t)(row0 + jj) * OUT_F + col] =
                    (float)acc[mi][ni][jj] * (sxq[jj] * inv) + bs;
        }
    }

    #undef LOAD_A
    #undef LOAD_B
    #undef CONVERT_B
    #undef MFMA_PHASE
}

// ---- Fallback (ws too small): R8 bf16 full-K kernel, LDS-staged operands ----
__global__ __launch_bounds__(128, 2)
void qgemm_fallback_kernel(const float* __restrict__ X,
                           const int*   __restrict__ W,
                           const float* __restrict__ scale,
                           const float* __restrict__ bias,
                           float* __restrict__ Out)
{
    __shared__ __align__(16) char smem[BM * BK * 2 + BN * BK * 2];
    char* bufA = smem;
    char* bufB = smem + BM * BK * 2;

    const int tid  = (int)threadIdx.x;
    const int lane = tid & 63;
    const int w    = tid >> 6;

    const int bid  = (int)blockIdx.x;
    const int lbid = (bid & 7) * 86 + (bid >> 3);
    const int mtile = lbid & 3;
    const int ntile = lbid >> 2;
    const int brow = mtile * BM;
    const int bcol = ntile * BN;

    const int srow  = tid >> 4;
    const int scol4 = tid & 15;
    const int* Wp = W + (size_t)(bcol + srow) * IN_F + scol4 * 4;
    const float* Xp = X + (size_t)(brow + srow) * IN_F + scol4 * 4;

    f32x4 acc[4][4];
    #pragma unroll
    for (int i = 0; i < 4; ++i)
        #pragma unroll
        for (int jj = 0; jj < 4; ++jj)
            acc[i][jj] = (f32x4){0.f, 0.f, 0.f, 0.f};

    for (int kt = 0; kt < NKT; ++kt) {
        #pragma unroll
        for (int k = 0; k < 8; ++k) {
            i32x4 rb = *(const i32x4*)(Wp + (size_t)kt * BK + (size_t)(k * 8) * IN_F);
            const int row = srow + k * 8;
            const int off = (row * 128 + scol4 * 8) ^ ((row & 7) << 4);
            u32x2 bv;
            bv.x = pack2bf16_exact((float)rb.x, (float)rb.y);
            bv.y = pack2bf16_exact((float)rb.z, (float)rb.w);
            *(u32x2*)(bufB + off) = bv;
        }
        #pragma unroll
        for (int k = 0; k < 16; ++k) {
            f32x4 ra = *(const f32x4*)(Xp + (size_t)kt * BK + (size_t)(k * 8) * IN_F);
            const int row = srow + k * 8;
            const int off = (row * 128 + scol4 * 8) ^ ((row & 7) << 4);
            u32x2 av;
            av.x = pack2bf16_rnd(ra.x, ra.y);
            av.y = pack2bf16_rnd(ra.z, ra.w);
            *(u32x2*)(bufA + off) = av;
        }
        __syncthreads();
        #pragma unroll
        for (int ks = 0; ks < 2; ++ks) {
            bf16x8 af[4], bfr[4];
            #pragma unroll
            for (int mi = 0; mi < 4; ++mi) {
                const int row = w * 64 + mi * 16 + (lane & 15);
                const int off = (row * 128 + ks * 64 + (lane >> 4) * 16)
                                ^ ((row & 7) << 4);
                af[mi] = *(const bf16x8*)(bufA + off);
            }
            #pragma unroll
            for (int ni = 0; ni < 4; ++ni) {
                const int row = ni * 16 + (lane & 15);
                const int off = (row * 128 + ks * 64 + (lane >> 4) * 16)
                                ^ ((row & 7) << 4);
                bfr[ni] = *(const bf16x8*)(bufB + off);
            }
            #pragma unroll
            for (int mi = 0; mi < 4; ++mi)
                #pragma unroll
                for (int ni = 0; ni < 4; ++ni)
                    acc[mi][ni] = __builtin_amdgcn_mfma_f32_16x16x32_bf16(
                        af[mi], bfr[ni], acc[mi][ni], 0, 0, 0);
        }
        __syncthreads();
    }

    #pragma unroll
    for (int ni = 0; ni < 4; ++ni) {
        const int col = bcol + ni * 16 + (lane & 15);
        const float inv = 1.0f / scale[col];
        const float bs  = bias[col];
        #pragma unroll
        for (int mi = 0; mi < 4; ++mi) {
            const int row0 = brow + w * 64 + mi * 16 + ((lane >> 4) << 2);
            #pragma unroll
            for (int jj = 0; jj < 4; ++jj)
                Out[(size_t)(row0 + jj) * OUT_F + col] = acc[mi][ni][jj] * inv + bs;
        }
    }
}

extern "C" void kernel_launch(void* const* d_in, const int* in_sizes, int n_in,
                              void* d_out, int out_size, void* d_ws, size_t ws_size,
                              hipStream_t stream) {
    const float* X     = (const float*)d_in[0];
    const int*   W     = (const int*)d_in[1];
    const float* scale = (const float*)d_in[2];
    const float* bias  = (const float*)d_in[3];
    float* Out = (float*)d_out;

    const int grid = (MTOT / BM) * (OUT_F / BN);  // 688 = 8*86

    if (ws_size >= X_WS_BYTES) {
        char*  xws = (char*)d_ws;
        float* sx  = (float*)((char*)d_ws + SX_OFF);
        xconv_kernel<<<MTOT, 256, 0, stream>>>(X, xws, sx);
        qgemm_kernel<<<grid, 128, 0, stream>>>(xws, sx, W, scale, bias, Out);
    } else {
        qgemm_fallback_kernel<<<grid, 128, 0, stream>>>(X, W, scale, bias, Out);
    }
}